// Round 1
// baseline (512.847 us; speedup 1.0000x reference)
//
#include <hip/hip_runtime.h>

typedef __bf16 bf16x8 __attribute__((ext_vector_type(8)));
typedef __bf16 bf16x4 __attribute__((ext_vector_type(4)));
typedef float floatx4 __attribute__((ext_vector_type(4)));

#define GK 2048
#define S_LEN 2048
#define NH 16
#define DH 128

__device__ __forceinline__ void gl2lds16(const __bf16* g, __bf16* l) {
    __builtin_amdgcn_global_load_lds(
        (const __attribute__((address_space(1))) void*)g,
        (__attribute__((address_space(3))) void*)l, 16, 0, 0);
}

// ---------------------------------------------------------------------------
// fp32 -> bf16 bulk convert (one float4 -> bf16x4 per thread)
// ---------------------------------------------------------------------------
__global__ __launch_bounds__(256) void cvt_bf16(const float* __restrict__ in,
                                                __bf16* __restrict__ out, int n4) {
    int i = blockIdx.x * 256 + threadIdx.x;
    if (i < n4) {
        const float4 v = ((const float4*)in)[i];
        bf16x4 h;
        h[0] = (__bf16)v.x; h[1] = (__bf16)v.y; h[2] = (__bf16)v.z; h[3] = (__bf16)v.w;
        ((bf16x4*)out)[i] = h;
    }
}

// concat-convert wq|wk|wv (each 2048x2048 fp32) -> one bf16 [6144][2048]
__global__ __launch_bounds__(256) void cvt3_bf16(const float* __restrict__ a,
                                                 const float* __restrict__ b,
                                                 const float* __restrict__ c,
                                                 __bf16* __restrict__ out) {
    const int per = 2048 * 2048 / 4;
    int i = blockIdx.x * 256 + threadIdx.x;      // 0 .. 3*per-1
    const float* src = a; int j = i;
    if (i >= 2 * per)      { src = c; j = i - 2 * per; }
    else if (i >= per)     { src = b; j = i - per; }
    const float4 v = ((const float4*)src)[j];
    bf16x4 h;
    h[0] = (__bf16)v.x; h[1] = (__bf16)v.y; h[2] = (__bf16)v.z; h[3] = (__bf16)v.w;
    ((bf16x4*)out)[i] = h;
}

// ---------------------------------------------------------------------------
// Pure-bf16 K-loop: C[m][n] = sum_k A[m][k] * W[n][k], both staged via
// global_load_lds width-16. 128x128 tile, BK=32, 4 waves, 4x4 MFMA/wave.
// ---------------------------------------------------------------------------
__device__ __forceinline__ void gemm_body(const __bf16* __restrict__ A,
                                          const __bf16* __restrict__ W,
                                          int m0, int n0,
                                          __bf16 (*As)[32], __bf16 (*Bs)[32],
                                          floatx4 (*acc)[4]) {
    const int t = threadIdx.x, lane = t & 63, wave = t >> 6;
    const int fr = lane & 15, fq = lane >> 4;
    const int wr = (wave >> 1) * 64, wc = (wave & 1) * 64;

    const __bf16* Ap = A + (size_t)(m0 + wave * 32 + (lane >> 2)) * GK + (lane & 3) * 8;
    const __bf16* Wp = W + (size_t)(n0 + wave * 32 + (lane >> 2)) * GK + (lane & 3) * 8;
    __bf16* lA0 = &As[wave * 32][0];
    __bf16* lA1 = &As[wave * 32 + 16][0];
    __bf16* lB0 = &Bs[wave * 32][0];
    __bf16* lB1 = &Bs[wave * 32 + 16][0];

    for (int k0 = 0; k0 < GK; k0 += 32) {
        gl2lds16(Ap, lA0);
        gl2lds16(Ap + (size_t)16 * GK, lA1);
        gl2lds16(Wp, lB0);
        gl2lds16(Wp + (size_t)16 * GK, lB1);
        Ap += 32; Wp += 32;
        __syncthreads();   // drains vmcnt + orders LDS

        bf16x8 af[4], bfg[4];
        for (int i = 0; i < 4; i++) af[i]  = *(const bf16x8*)&As[wr + i * 16 + fr][fq * 8];
        for (int j = 0; j < 4; j++) bfg[j] = *(const bf16x8*)&Bs[wc + j * 16 + fr][fq * 8];
        for (int i = 0; i < 4; i++)
            for (int j = 0; j < 4; j++)
                acc[i][j] = __builtin_amdgcn_mfma_f32_16x16x32_bf16(af[i], bfg[j], acc[i][j], 0, 0, 0);
        __syncthreads();
    }
}

// Fused QKV projection: A (4096x2048 bf16) x Wqkv (6144x2048 bf16).
// n<2048 -> qb, n<4096 -> kb (row-major [b*S][2048]); n>=4096 -> vbT
// ([b][h*128+d][s], transposed for flash staging).
__global__ __launch_bounds__(256) void gemm_qkv(const __bf16* __restrict__ A,
                                                const __bf16* __restrict__ W,
                                                __bf16* __restrict__ qb,
                                                __bf16* __restrict__ kb,
                                                __bf16* __restrict__ vbT) {
    __shared__ __align__(16) __bf16 As[128][32];
    __shared__ __align__(16) __bf16 Bs[128][32];
    const int m0 = blockIdx.y * 128, n0 = blockIdx.x * 128;
    floatx4 acc[4][4] = {};
    gemm_body(A, W, m0, n0, As, Bs, acc);

    const int lane = threadIdx.x & 63, wave = threadIdx.x >> 6;
    const int fr = lane & 15, fq = lane >> 4;
    const int wr = (wave >> 1) * 64, wc = (wave & 1) * 64;
    const int which = n0 >> 11;          // 0=q 1=k 2=v (block-uniform)
    const int nc0 = n0 & 2047;

    for (int i = 0; i < 4; i++)
        for (int j = 0; j < 4; j++) {
            const int row = m0 + wr + i * 16 + fq * 4;
            const int col = nc0 + wc + j * 16 + fr;
            if (which == 2) {
                // vbT[b][col][s]; b = row>>11, s = row&2047 (row%4==0 -> 8B aligned)
                __bf16* Cp = vbT + (((size_t)(row & ~2047)) << 11) +
                             (size_t)col * 2048 + (row & 2047);
                bf16x4 hv;
                for (int r = 0; r < 4; r++) hv[r] = (__bf16)acc[i][j][r];
                *(bf16x4*)Cp = hv;
            } else {
                __bf16* dst = which ? kb : qb;
                for (int r = 0; r < 4; r++)
                    dst[(size_t)(row + r) * 2048 + col] = (__bf16)acc[i][j][r];
            }
        }
}

// Out-projection: A (4096x2048 bf16) x Wo (2048x2048 bf16) -> fp32 out
__global__ __launch_bounds__(256) void gemm_out(const __bf16* __restrict__ A,
                                                const __bf16* __restrict__ W,
                                                float* __restrict__ C) {
    __shared__ __align__(16) __bf16 As[128][32];
    __shared__ __align__(16) __bf16 Bs[128][32];
    const int m0 = blockIdx.y * 128, n0 = blockIdx.x * 128;
    floatx4 acc[4][4] = {};
    gemm_body(A, W, m0, n0, As, Bs, acc);

    const int lane = threadIdx.x & 63, wave = threadIdx.x >> 6;
    const int fr = lane & 15, fq = lane >> 4;
    const int wr = (wave >> 1) * 64, wc = (wave & 1) * 64;
    for (int i = 0; i < 4; i++)
        for (int j = 0; j < 4; j++) {
            const int row = m0 + wr + i * 16 + fq * 4;
            const int col = n0 + wc + j * 16 + fr;
            for (int r = 0; r < 4; r++)
                C[(size_t)(row + r) * 2048 + col] = acc[i][j][r];
        }
}

// ---------------------------------------------------------------------------
// Fused RMSNorm (per head, DH=128, fp32 math) + RoPE, in-place on bf16 q/k.
// ---------------------------------------------------------------------------
__global__ __launch_bounds__(256) void rmsrope(__bf16* __restrict__ qb,
                                               __bf16* __restrict__ kb,
                                               const float* __restrict__ rope,
                                               const float* __restrict__ qw,
                                               const float* __restrict__ kw) {
    const int lane = threadIdx.x & 63;
    const int row = blockIdx.x * 4 + (threadIdx.x >> 6);   // (b*S + s)*H + h
    __bf16* p = (blockIdx.y ? kb : qb) + (size_t)row * DH;
    const float* w = blockIdx.y ? kw : qw;
    const int s = (row >> 4) & (S_LEN - 1);

    float t0 = (float)p[lane];
    float t1 = (float)p[lane + 64];
    float ss = t0 * t0 + t1 * t1;
    for (int o = 32; o; o >>= 1) ss += __shfl_xor(ss, o, 64);
    const float inv = rsqrtf(ss * (1.0f / 128.0f) + 1e-6f);
    t0 *= inv * w[lane];
    t1 *= inv * w[lane + 64];

    const float4 f = *(const float4*)(rope + (size_t)s * 256 + lane * 4);
    p[lane]      = (__bf16)(f.x * t0 + f.y * t1);
    p[lane + 64] = (__bf16)(f.z * t0 + f.w * t1);
}

// ---------------------------------------------------------------------------
// Flash attention v2: fixed-max softmax (p = exp2(s*sc*log2e - M2)), l via
// MFMA ones-column. grid = (S/128, B*H), 4 waves x 32 q-rows.
//   - KVBLK=64 (halves barrier count: 64 -> 32 iters, 2 barriers each)
//   - reg-staged K/V with issue-early/write-late (T14): next tile's global
//     loads are in flight across the whole compute phase
//   - unpadded [row][128B] LDS tiles with XOR swizzle byte^=(row&7)<<4 on
//     both write and read (T2) -> ~2-way max on ds_read_b128
//   - s_setprio(1) around QK and PV MFMA clusters (T5)
//   - XCD-grouped block remap: all 16 q-blocks of 4 heads share one XCD's L2
//     (KV footprint 4 MB = one L2) to cut HBM re-fetch + staging latency
// ---------------------------------------------------------------------------
__global__ __launch_bounds__(256, 2) void flash(const __bf16* __restrict__ Q,
                                                const __bf16* __restrict__ K,
                                                const __bf16* __restrict__ Vt_g,
                                                __bf16* __restrict__ O) {
    __shared__ __align__(16) __bf16 Ks[64][128];    // [kv][d]   16 KB
    __shared__ __align__(16) __bf16 Vt[144][64];    // [d][kv]   18 KB (+ones rows)
    __shared__ __align__(16) __bf16 Ps[4][32][72];  // per-wave P, stride 72  18 KB

    const int t = threadIdx.x, lane = t & 63, wave = t >> 6;
    const int fr = lane & 15, fq = lane >> 4;

    // XCD-aware remap: hw assigns block n -> XCD n%8. Give each XCD 4 heads
    // x 16 q-blocks so the shared K/V (4 MB) lives in that XCD's L2.
    const int n = blockIdx.x + (int)gridDim.x * blockIdx.y;   // 0..511
    const int by = (n & 7) * 4 + (n >> 7);                    // b*16+h, 0..31
    const int bx = (n >> 3) & 15;                             // q-block, 0..15
    const int b = by >> 4, h = by & 15;

    const size_t baseQ = (size_t)b * S_LEN * 2048 + h * 128;
    const size_t baseV = (size_t)b * 2048 * 2048 + (size_t)h * 128 * 2048;
    const int q0 = bx * 128 + wave * 32;
    const float sc2 = 0.08838834764831845f * 1.4426950408889634f;  // (1/sqrt(128))*log2e
    const float M2 = 12.0f * 1.4426950408889634f;

    // ones rows for l-sum (Vt rows 128..143): row 128 = 1.0, rest 0.
    // Row-constant data is invariant under the within-row XOR swizzle.
    if (t < 128) {
        const int rr = 128 + (t >> 3), cb = (t & 7) * 8;
        bf16x8 v;
        for (int e = 0; e < 8; e++) v[e] = (rr == 128) ? (__bf16)1.0f : (__bf16)0.0f;
        *(bf16x8*)&Vt[rr][cb] = v;
    }

    // Q fragments (registers, whole loop)
    bf16x8 qf[2][4];
    for (int i2 = 0; i2 < 2; i2++) {
        const __bf16* qp = Q + baseQ + (size_t)(q0 + i2 * 16 + fr) * 2048 + fq * 8;
        for (int c = 0; c < 4; c++) qf[i2][c] = *(const bf16x8*)(qp + c * 32);
    }

    floatx4 oa[2][9] = {};

    // staging geometry: K tile 64 rows x 256B, V tile 128 rows x 128B
    const int kR  = t >> 4;          // + ch*16
    const int kCb = (t & 15) * 16;   // byte col in row
    const int vR  = t >> 3;          // + ch*32
    const int vCb = (t & 7) * 16;

    const __bf16* gK = K + baseQ + (size_t)kR * 2048 + (kCb >> 1);
    const __bf16* gV = Vt_g + baseV + (size_t)vR * 2048 + (vCb >> 1);

    char* KsB = (char*)&Ks[0][0];
    char* VtB = (char*)&Vt[0][0];

    // prologue: tile 0 into regs
    uint4 rk[4], rv[4];
#pragma unroll
    for (int ch = 0; ch < 4; ch++) rk[ch] = *(const uint4*)(gK + (size_t)ch * 16 * 2048);
#pragma unroll
    for (int ch = 0; ch < 4; ch++) rv[ch] = *(const uint4*)(gV + (size_t)ch * 32 * 2048);

    for (int it = 0; it < 32; it++) {
        __syncthreads();   // all waves done reading LDS from previous iter
#pragma unroll
        for (int ch = 0; ch < 4; ch++) {
            const int R = kR + ch * 16;
            *(uint4*)(KsB + R * 256 + (kCb ^ ((R & 7) << 4))) = rk[ch];
        }
#pragma unroll
        for (int ch = 0; ch < 4; ch++) {
            const int R = vR + ch * 32;
            *(uint4*)(VtB + R * 128 + (vCb ^ ((R & 7) << 4))) = rv[ch];
        }
        if (it < 31) {   // issue next tile NOW; lands during compute (T14)
            gK += (size_t)64 * 2048;
            gV += 64;
#pragma unroll
            for (int ch = 0; ch < 4; ch++) rk[ch] = *(const uint4*)(gK + (size_t)ch * 16 * 2048);
#pragma unroll
            for (int ch = 0; ch < 4; ch++) rv[ch] = *(const uint4*)(gV + (size_t)ch * 32 * 2048);
        }
        __syncthreads();   // publish LDS tile

        // ---- QK^T: S[q][kv] over 64 kv ----
        floatx4 sacc[2][4] = {};
        const int sw = (fr & 7) << 4;
        __builtin_amdgcn_s_setprio(1);
#pragma unroll
        for (int j = 0; j < 4; j++) {
            const char* kb = KsB + (j * 16 + fr) * 256;
#pragma unroll
            for (int c = 0; c < 4; c++) {
                const bf16x8 kf = *(const bf16x8*)(kb + ((c * 64 + fq * 16) ^ sw));
                sacc[0][j] = __builtin_amdgcn_mfma_f32_16x16x32_bf16(qf[0][c], kf, sacc[0][j], 0, 0, 0);
                sacc[1][j] = __builtin_amdgcn_mfma_f32_16x16x32_bf16(qf[1][c], kf, sacc[1][j], 0, 0, 0);
            }
        }
        __builtin_amdgcn_s_setprio(0);

        // ---- softmax (fixed max), P -> LDS ----
#pragma unroll
        for (int i2 = 0; i2 < 2; i2++)
#pragma unroll
            for (int r = 0; r < 4; r++) {
                const int row = i2 * 16 + fq * 4 + r;
#pragma unroll
                for (int j = 0; j < 4; j++)
                    Ps[wave][row][j * 16 + fr] = (__bf16)exp2f(fmaf(sc2, sacc[i2][j][r], -M2));
            }

        // ---- PV ----
        bf16x8 pf[2][2];
#pragma unroll
        for (int i2 = 0; i2 < 2; i2++)
#pragma unroll
            for (int kc = 0; kc < 2; kc++)
                pf[i2][kc] = *(const bf16x8*)&Ps[wave][i2 * 16 + fr][kc * 32 + fq * 8];

        __builtin_amdgcn_s_setprio(1);
#pragma unroll
        for (int nb = 0; nb < 9; nb++) {
            const char* vb = VtB + (nb * 16 + fr) * 128;
#pragma unroll
            for (int kc = 0; kc < 2; kc++) {
                const bf16x8 vf = *(const bf16x8*)(vb + ((kc * 64 + fq * 16) ^ sw));
                oa[0][nb] = __builtin_amdgcn_mfma_f32_16x16x32_bf16(pf[0][kc], vf, oa[0][nb], 0, 0, 0);
                oa[1][nb] = __builtin_amdgcn_mfma_f32_16x16x32_bf16(pf[1][kc], vf, oa[1][nb], 0, 0, 0);
            }
        }
        __builtin_amdgcn_s_setprio(0);
    }

    for (int i2 = 0; i2 < 2; i2++)
        for (int r = 0; r < 4; r++) {
            float l = oa[i2][8][r];
            l = __shfl(l, fq * 16);
            const float inv = 1.0f / l;
            __bf16* op = O + baseQ + (size_t)(q0 + i2 * 16 + fq * 4 + r) * 2048;
            for (int nb = 0; nb < 8; nb++)
                op[nb * 16 + fr] = (__bf16)(oa[i2][nb][r] * inv);
        }
}

// ---------------------------------------------------------------------------
extern "C" void kernel_launch(void* const* d_in, const int* in_sizes, int n_in,
                              void* d_out, int out_size, void* d_ws, size_t ws_size,
                              hipStream_t stream) {
    const float* x    = (const float*)d_in[0];
    const float* rope = (const float*)d_in[1];
    const float* wq   = (const float*)d_in[2];
    const float* wk   = (const float*)d_in[3];
    const float* wv   = (const float*)d_in[4];
    const float* wo   = (const float*)d_in[5];
    const float* qnw  = (const float*)d_in[6];
    const float* knw  = (const float*)d_in[7];
    float* out = (float*)d_out;

    const size_t NTOK = 2 * 2048;
    const size_t ELEMS = NTOK * 2048;            // 8388608
    __bf16* xb  = (__bf16*)d_ws;                 // 16 MB; reused as ob after flash
    __bf16* qb  = xb + ELEMS;                    // 16 MB; reused for wo_bf after flash
    __bf16* kb  = qb + ELEMS;
    __bf16* vbT = kb + ELEMS;
    __bf16* ob  = xb;
    // d_out (32 MB fp32) doubles as scratch for the concatenated bf16 QKV
    // weights (25.2 MB) — fully consumed by gemm_qkv before gemm_out writes it.
    __bf16* wqkv = (__bf16*)d_out;
    __bf16* wob  = qb;                           // wo bf16 (8 MB), written after flash

    cvt_bf16<<<(int)(ELEMS / 4) / 256, 256, 0, stream>>>(x, xb, (int)(ELEMS / 4));
    cvt3_bf16<<<3 * (2048 * 2048 / 4) / 256, 256, 0, stream>>>(wq, wk, wv, wqkv);
    gemm_qkv<<<dim3(6144 / 128, (unsigned)(NTOK / 128)), 256, 0, stream>>>(xb, wqkv, qb, kb, vbT);
    rmsrope<<<dim3((unsigned)(NTOK * 16 / 4), 2), 256, 0, stream>>>(qb, kb, rope, qnw, knw);
    flash<<<dim3(S_LEN / 128, 2 * 16), 256, 0, stream>>>(qb, kb, vbT, ob);
    cvt_bf16<<<(int)(2048 * 2048 / 4) / 256, 256, 0, stream>>>(wo, wob, 2048 * 2048 / 4);
    gemm_out<<<dim3(2048 / 128, (unsigned)(NTOK / 128)), 256, 0, stream>>>(ob, wob, out);
}

// Round 2
// 450.855 us; speedup vs baseline: 1.1375x; 1.1375x over previous
//
#include <hip/hip_runtime.h>

typedef __bf16 bf16x8 __attribute__((ext_vector_type(8)));
typedef __bf16 bf16x4 __attribute__((ext_vector_type(4)));
typedef float floatx4 __attribute__((ext_vector_type(4)));

#define GK 2048
#define S_LEN 2048
#define NH 16
#define DH 128

__device__ __forceinline__ void gl2lds16(const __bf16* g, __bf16* l) {
    __builtin_amdgcn_global_load_lds(
        (const __attribute__((address_space(1))) void*)g,
        (__attribute__((address_space(3))) void*)l, 16, 0, 0);
}

// ---------------------------------------------------------------------------
// fp32 -> bf16 bulk convert (one float4 -> bf16x4 per thread)
// ---------------------------------------------------------------------------
__global__ __launch_bounds__(256) void cvt_bf16(const float* __restrict__ in,
                                                __bf16* __restrict__ out, int n4) {
    int i = blockIdx.x * 256 + threadIdx.x;
    if (i < n4) {
        const float4 v = ((const float4*)in)[i];
        bf16x4 h;
        h[0] = (__bf16)v.x; h[1] = (__bf16)v.y; h[2] = (__bf16)v.z; h[3] = (__bf16)v.w;
        ((bf16x4*)out)[i] = h;
    }
}

// concat-convert wq|wk|wv (each 2048x2048 fp32) -> one bf16 [6144][2048]
__global__ __launch_bounds__(256) void cvt3_bf16(const float* __restrict__ a,
                                                 const float* __restrict__ b,
                                                 const float* __restrict__ c,
                                                 __bf16* __restrict__ out) {
    const int per = 2048 * 2048 / 4;
    int i = blockIdx.x * 256 + threadIdx.x;      // 0 .. 3*per-1
    const float* src = a; int j = i;
    if (i >= 2 * per)      { src = c; j = i - 2 * per; }
    else if (i >= per)     { src = b; j = i - per; }
    const float4 v = ((const float4*)src)[j];
    bf16x4 h;
    h[0] = (__bf16)v.x; h[1] = (__bf16)v.y; h[2] = (__bf16)v.z; h[3] = (__bf16)v.w;
    ((bf16x4*)out)[i] = h;
}

// ---------------------------------------------------------------------------
// Pure-bf16 K-loop: C[m][n] = sum_k A[m][k] * W[n][k], both staged via
// global_load_lds width-16. 128x128 tile, BK=32, 4 waves, 4x4 MFMA/wave.
// ---------------------------------------------------------------------------
__device__ __forceinline__ void gemm_body(const __bf16* __restrict__ A,
                                          const __bf16* __restrict__ W,
                                          int m0, int n0,
                                          __bf16 (*As)[32], __bf16 (*Bs)[32],
                                          floatx4 (*acc)[4]) {
    const int t = threadIdx.x, lane = t & 63, wave = t >> 6;
    const int fr = lane & 15, fq = lane >> 4;
    const int wr = (wave >> 1) * 64, wc = (wave & 1) * 64;

    const __bf16* Ap = A + (size_t)(m0 + wave * 32 + (lane >> 2)) * GK + (lane & 3) * 8;
    const __bf16* Wp = W + (size_t)(n0 + wave * 32 + (lane >> 2)) * GK + (lane & 3) * 8;
    __bf16* lA0 = &As[wave * 32][0];
    __bf16* lA1 = &As[wave * 32 + 16][0];
    __bf16* lB0 = &Bs[wave * 32][0];
    __bf16* lB1 = &Bs[wave * 32 + 16][0];

    for (int k0 = 0; k0 < GK; k0 += 32) {
        gl2lds16(Ap, lA0);
        gl2lds16(Ap + (size_t)16 * GK, lA1);
        gl2lds16(Wp, lB0);
        gl2lds16(Wp + (size_t)16 * GK, lB1);
        Ap += 32; Wp += 32;
        __syncthreads();   // drains vmcnt + orders LDS

        bf16x8 af[4], bfg[4];
        for (int i = 0; i < 4; i++) af[i]  = *(const bf16x8*)&As[wr + i * 16 + fr][fq * 8];
        for (int j = 0; j < 4; j++) bfg[j] = *(const bf16x8*)&Bs[wc + j * 16 + fr][fq * 8];
        __builtin_amdgcn_s_setprio(1);
        for (int i = 0; i < 4; i++)
            for (int j = 0; j < 4; j++)
                acc[i][j] = __builtin_amdgcn_mfma_f32_16x16x32_bf16(af[i], bfg[j], acc[i][j], 0, 0, 0);
        __builtin_amdgcn_s_setprio(0);
        __syncthreads();
    }
}

// XCD-aware bijective remap of a linear block id (nwg must be %8==0).
__device__ __forceinline__ int xcd_remap(int L, int nwg) {
    return (L & 7) * (nwg >> 3) + (L >> 3);
}

// Fused QKV projection: A (4096x2048 bf16) x Wqkv (6144x2048 bf16).
// n<2048 -> qb, n<4096 -> kb (row-major [b*S][2048]); n>=4096 -> vbT
// ([b][h*128+d][s], transposed for flash staging).
__global__ __launch_bounds__(256) void gemm_qkv(const __bf16* __restrict__ A,
                                                const __bf16* __restrict__ W,
                                                __bf16* __restrict__ qb,
                                                __bf16* __restrict__ kb,
                                                __bf16* __restrict__ vbT) {
    __shared__ __align__(16) __bf16 As[128][32];
    __shared__ __align__(16) __bf16 Bs[128][32];
    const int L = blockIdx.x + (int)gridDim.x * blockIdx.y;
    const int tid2 = xcd_remap(L, (int)(gridDim.x * gridDim.y));
    const int m0 = (tid2 / (int)gridDim.x) * 128, n0 = (tid2 % (int)gridDim.x) * 128;
    floatx4 acc[4][4] = {};
    gemm_body(A, W, m0, n0, As, Bs, acc);

    const int lane = threadIdx.x & 63, wave = threadIdx.x >> 6;
    const int fr = lane & 15, fq = lane >> 4;
    const int wr = (wave >> 1) * 64, wc = (wave & 1) * 64;
    const int which = n0 >> 11;          // 0=q 1=k 2=v (block-uniform)
    const int nc0 = n0 & 2047;

    for (int i = 0; i < 4; i++)
        for (int j = 0; j < 4; j++) {
            const int row = m0 + wr + i * 16 + fq * 4;
            const int col = nc0 + wc + j * 16 + fr;
            if (which == 2) {
                // vbT[b][col][s]; b = row>>11, s = row&2047 (row%4==0 -> 8B aligned)
                __bf16* Cp = vbT + (((size_t)(row & ~2047)) << 11) +
                             (size_t)col * 2048 + (row & 2047);
                bf16x4 hv;
                for (int r = 0; r < 4; r++) hv[r] = (__bf16)acc[i][j][r];
                *(bf16x4*)Cp = hv;
            } else {
                __bf16* dst = which ? kb : qb;
                for (int r = 0; r < 4; r++)
                    dst[(size_t)(row + r) * 2048 + col] = (__bf16)acc[i][j][r];
            }
        }
}

// Out-projection: A (4096x2048 bf16) x Wo (2048x2048 bf16) -> fp32 out
__global__ __launch_bounds__(256) void gemm_out(const __bf16* __restrict__ A,
                                                const __bf16* __restrict__ W,
                                                float* __restrict__ C) {
    __shared__ __align__(16) __bf16 As[128][32];
    __shared__ __align__(16) __bf16 Bs[128][32];
    const int L = blockIdx.x + (int)gridDim.x * blockIdx.y;
    const int tid2 = xcd_remap(L, (int)(gridDim.x * gridDim.y));
    const int m0 = (tid2 / (int)gridDim.x) * 128, n0 = (tid2 % (int)gridDim.x) * 128;
    floatx4 acc[4][4] = {};
    gemm_body(A, W, m0, n0, As, Bs, acc);

    const int lane = threadIdx.x & 63, wave = threadIdx.x >> 6;
    const int fr = lane & 15, fq = lane >> 4;
    const int wr = (wave >> 1) * 64, wc = (wave & 1) * 64;
    for (int i = 0; i < 4; i++)
        for (int j = 0; j < 4; j++) {
            const int row = m0 + wr + i * 16 + fq * 4;
            const int col = n0 + wc + j * 16 + fr;
            for (int r = 0; r < 4; r++)
                C[(size_t)(row + r) * 2048 + col] = acc[i][j][r];
        }
}

// ---------------------------------------------------------------------------
// Fused RMSNorm (per head, DH=128, fp32 math) + RoPE, in-place on bf16 q/k.
// ---------------------------------------------------------------------------
__global__ __launch_bounds__(256) void rmsrope(__bf16* __restrict__ qb,
                                               __bf16* __restrict__ kb,
                                               const float* __restrict__ rope,
                                               const float* __restrict__ qw,
                                               const float* __restrict__ kw) {
    const int lane = threadIdx.x & 63;
    const int row = blockIdx.x * 4 + (threadIdx.x >> 6);   // (b*S + s)*H + h
    __bf16* p = (blockIdx.y ? kb : qb) + (size_t)row * DH;
    const float* w = blockIdx.y ? kw : qw;
    const int s = (row >> 4) & (S_LEN - 1);

    float t0 = (float)p[lane];
    float t1 = (float)p[lane + 64];
    float ss = t0 * t0 + t1 * t1;
    for (int o = 32; o; o >>= 1) ss += __shfl_xor(ss, o, 64);
    const float inv = rsqrtf(ss * (1.0f / 128.0f) + 1e-6f);
    t0 *= inv * w[lane];
    t1 *= inv * w[lane + 64];

    const float4 f = *(const float4*)(rope + (size_t)s * 256 + lane * 4);
    p[lane]      = (__bf16)(f.x * t0 + f.y * t1);
    p[lane + 64] = (__bf16)(f.z * t0 + f.w * t1);
}

// ---------------------------------------------------------------------------
// Flash attention (round-0 body + T1 XCD remap + T5 setprio):
// fixed-max softmax (p = exp2(s*sc*log2e - M2)), l via MFMA ones-column.
// grid = (S/128, B*H), 4 waves x 32 q-rows, KV tile 32.
// XCD remap: all 16 q-blocks of 4 heads share one XCD -> K/V (4 MB) lives in
// that XCD's L2 (round-1 evidence: FETCH 139 MB -> 33 MB).
// ---------------------------------------------------------------------------
__global__ __launch_bounds__(256) void flash(const __bf16* __restrict__ Q,
                                             const __bf16* __restrict__ K,
                                             const __bf16* __restrict__ Vt_g,
                                             __bf16* __restrict__ O) {
    __shared__ __align__(16) __bf16 Ks[32][136];
    __shared__ __align__(16) __bf16 Vt[144][40];
    __shared__ __align__(16) __bf16 Ps[4][32][40];

    const int t = threadIdx.x, lane = t & 63, wave = t >> 6;
    const int fr = lane & 15, fq = lane >> 4;

    const int n = blockIdx.x + (int)gridDim.x * blockIdx.y;   // 0..511
    const int by = (n & 7) * 4 + (n >> 7);                    // b*16+h, 0..31
    const int bx = (n >> 3) & 15;                             // q-block, 0..15
    const int b = by >> 4, h = by & 15;

    const size_t baseQ = (size_t)b * S_LEN * 2048 + h * 128;
    const size_t baseV = (size_t)b * 2048 * 2048 + (size_t)h * 128 * 2048;
    const int q0 = bx * 128 + wave * 32;
    const float sc2 = 0.08838834764831845f * 1.4426950408889634f;  // (1/sqrt(128))*log2e
    const float M2 = 12.0f * 1.4426950408889634f;

    for (int idx = t; idx < 16 * 40; idx += 256) {
        const int rr = idx / 40, cc = idx - rr * 40;
        Vt[128 + rr][cc] = (rr == 0) ? (__bf16)1.0f : (__bf16)0.0f;
    }

    bf16x8 qf[2][4];
    for (int i2 = 0; i2 < 2; i2++) {
        const __bf16* qp = Q + baseQ + (size_t)(q0 + i2 * 16 + fr) * 2048 + fq * 8;
        for (int c = 0; c < 4; c++) qf[i2][c] = *(const bf16x8*)(qp + c * 32);
    }

    floatx4 oa[2][9] = {};

    const __bf16* Kp = K + baseQ + (size_t)(t >> 3) * 2048 + (t & 7) * 16;
    const __bf16* Vp = Vt_g + baseV + (size_t)(t >> 1) * 2048 + (t & 1) * 16;

    for (int kv0 = 0; kv0 < S_LEN; kv0 += 32) {
        *(uint4*)&Ks[t >> 3][(t & 7) * 16]     = *(const uint4*)(Kp);
        *(uint4*)&Ks[t >> 3][(t & 7) * 16 + 8] = *(const uint4*)(Kp + 8);
        *(uint4*)&Vt[t >> 1][(t & 1) * 16]     = *(const uint4*)(Vp);
        *(uint4*)&Vt[t >> 1][(t & 1) * 16 + 8] = *(const uint4*)(Vp + 8);
        Kp += (size_t)32 * 2048;
        Vp += 32;
        __syncthreads();

        floatx4 sacc[2][2] = {};
        __builtin_amdgcn_s_setprio(1);
        for (int c = 0; c < 4; c++) {
            const bf16x8 kf0 = *(const bf16x8*)&Ks[fr][c * 32 + fq * 8];
            const bf16x8 kf1 = *(const bf16x8*)&Ks[fr + 16][c * 32 + fq * 8];
            sacc[0][0] = __builtin_amdgcn_mfma_f32_16x16x32_bf16(qf[0][c], kf0, sacc[0][0], 0, 0, 0);
            sacc[0][1] = __builtin_amdgcn_mfma_f32_16x16x32_bf16(qf[0][c], kf1, sacc[0][1], 0, 0, 0);
            sacc[1][0] = __builtin_amdgcn_mfma_f32_16x16x32_bf16(qf[1][c], kf0, sacc[1][0], 0, 0, 0);
            sacc[1][1] = __builtin_amdgcn_mfma_f32_16x16x32_bf16(qf[1][c], kf1, sacc[1][1], 0, 0, 0);
        }
        __builtin_amdgcn_s_setprio(0);

        for (int i2 = 0; i2 < 2; i2++)
            for (int r = 0; r < 4; r++) {
                const int row = i2 * 16 + fq * 4 + r;
                Ps[wave][row][fr]      = (__bf16)exp2f(fmaf(sc2, sacc[i2][0][r], -M2));
                Ps[wave][row][fr + 16] = (__bf16)exp2f(fmaf(sc2, sacc[i2][1][r], -M2));
            }

        const bf16x8 pf0 = *(const bf16x8*)&Ps[wave][fr][fq * 8];
        const bf16x8 pf1 = *(const bf16x8*)&Ps[wave][16 + fr][fq * 8];
        __builtin_amdgcn_s_setprio(1);
        for (int nb = 0; nb < 9; nb++) {
            const bf16x8 vf = *(const bf16x8*)&Vt[nb * 16 + fr][fq * 8];
            oa[0][nb] = __builtin_amdgcn_mfma_f32_16x16x32_bf16(pf0, vf, oa[0][nb], 0, 0, 0);
            oa[1][nb] = __builtin_amdgcn_mfma_f32_16x16x32_bf16(pf1, vf, oa[1][nb], 0, 0, 0);
        }
        __builtin_amdgcn_s_setprio(0);
        __syncthreads();
    }

    for (int i2 = 0; i2 < 2; i2++)
        for (int r = 0; r < 4; r++) {
            float l = oa[i2][8][r];
            l = __shfl(l, fq * 16);
            const float inv = 1.0f / l;
            __bf16* op = O + baseQ + (size_t)(q0 + i2 * 16 + fq * 4 + r) * 2048;
            for (int nb = 0; nb < 8; nb++)
                op[nb * 16 + fr] = (__bf16)(oa[i2][nb][r] * inv);
        }
}

// ---------------------------------------------------------------------------
extern "C" void kernel_launch(void* const* d_in, const int* in_sizes, int n_in,
                              void* d_out, int out_size, void* d_ws, size_t ws_size,
                              hipStream_t stream) {
    const float* x    = (const float*)d_in[0];
    const float* rope = (const float*)d_in[1];
    const float* wq   = (const float*)d_in[2];
    const float* wk   = (const float*)d_in[3];
    const float* wv   = (const float*)d_in[4];
    const float* wo   = (const float*)d_in[5];
    const float* qnw  = (const float*)d_in[6];
    const float* knw  = (const float*)d_in[7];
    float* out = (float*)d_out;

    const size_t NTOK = 2 * 2048;
    const size_t ELEMS = NTOK * 2048;            // 8388608
    __bf16* xb  = (__bf16*)d_ws;                 // 16 MB; reused as ob after flash
    __bf16* qb  = xb + ELEMS;                    // 16 MB; reused for wo_bf after flash
    __bf16* kb  = qb + ELEMS;
    __bf16* vbT = kb + ELEMS;
    __bf16* ob  = xb;
    // d_out (32 MB fp32) doubles as scratch for the concatenated bf16 QKV
    // weights (25.2 MB) — fully consumed by gemm_qkv before gemm_out writes it.
    __bf16* wqkv = (__bf16*)d_out;
    __bf16* wob  = qb;                           // wo bf16 (8 MB), written after flash

    cvt_bf16<<<(int)(ELEMS / 4) / 256, 256, 0, stream>>>(x, xb, (int)(ELEMS / 4));
    cvt3_bf16<<<3 * (2048 * 2048 / 4) / 256, 256, 0, stream>>>(wq, wk, wv, wqkv);
    gemm_qkv<<<dim3(6144 / 128, (unsigned)(NTOK / 128)), 256, 0, stream>>>(xb, wqkv, qb, kb, vbT);
    rmsrope<<<dim3((unsigned)(NTOK * 16 / 4), 2), 256, 0, stream>>>(qb, kb, rope, qnw, knw);
    flash<<<dim3(S_LEN / 128, 2 * 16), 256, 0, stream>>>(qb, kb, vbT, ob);
    cvt_bf16<<<(int)(2048 * 2048 / 4) / 256, 256, 0, stream>>>(wo, wob, 2048 * 2048 / 4);
    gemm_out<<<dim3(2048 / 128, (unsigned)(NTOK / 128)), 256, 0, stream>>>(ob, wob, out);
}